// Round 1
// baseline (262.728 us; speedup 1.0000x reference)
//
#include <hip/hip_runtime.h>
#include <math.h>

#define BATCH 32
#define CH    256
#define HH    56
#define WW    56
#define HW    3136
#define KS    7
#define KK    49
#define NIMG  8192          // BATCH*CH
#define PITCH 64            // padded LDS row pitch (floats)
#define PROWS 62            // 56 + 2*3 pad rows

// ---------------- Kernel 1: 8x8 block-mean pool -> p[B,C,49] ----------------
__global__ __launch_bounds__(256) void pool_kernel(const float* __restrict__ x,
                                                   float* __restrict__ p) {
    __shared__ float tile[HW];
    const int img = blockIdx.x;
    const float* xi = x + (size_t)img * HW;
    for (int i = threadIdx.x; i < HW; i += 256) tile[i] = xi[i];
    __syncthreads();
    if (threadIdx.x < KK) {
        const int pr = threadIdx.x / KS, pc = threadIdx.x % KS;
        float s = 0.f;
        #pragma unroll
        for (int r = 0; r < 8; ++r) {
            const int base = (pr * 8 + r) * WW + pc * 8;
            #pragma unroll
            for (int c = 0; c < 8; ++c) s += tile[base + c];
        }
        p[(size_t)img * KK + threadIdx.x] = s * (1.0f / 64.0f);
    }
}

// ------------- Kernel 2: BN batch stats per channel -> scale/shift ----------
__global__ __launch_bounds__(256) void bnstats_kernel(const float* __restrict__ p,
                                                      const float* __restrict__ gamma,
                                                      const float* __restrict__ beta,
                                                      float* __restrict__ scale,
                                                      float* __restrict__ shift) {
    const int c = blockIdx.x;
    float s = 0.f, s2 = 0.f;
    for (int t = threadIdx.x; t < BATCH * KK; t += 256) {
        const int b = t / KK, i = t - b * KK;
        const float v = p[((size_t)b * CH + c) * KK + i];
        s += v; s2 += v * v;
    }
    #pragma unroll
    for (int o = 32; o >= 1; o >>= 1) {
        s  += __shfl_down(s, o, 64);
        s2 += __shfl_down(s2, o, 64);
    }
    __shared__ float r1[4], r2[4];
    const int w = threadIdx.x >> 6;
    if ((threadIdx.x & 63) == 0) { r1[w] = s; r2[w] = s2; }
    __syncthreads();
    if (threadIdx.x == 0) {
        const float S  = r1[0] + r1[1] + r1[2] + r1[3];
        const float S2 = r2[0] + r2[1] + r2[2] + r2[3];
        const float inv = 1.0f / (float)(BATCH * KK);
        const float mu  = S * inv;
        const float var = S2 * inv - mu * mu;       // biased, matches ref
        const float rstd = rsqrtf(var + 1e-5f);
        const float sc = gamma[c] * rstd;
        scale[c] = sc;
        shift[c] = beta[c] - mu * sc;
    }
}

// --- Kernel 3: BN-apply + Linear(49->7) + LayerNorm(C,7) + sigmoid + Linear(7->49) ---
// one block per batch sample b; thread = channel c
__global__ __launch_bounds__(256) void mid_kernel(const float* __restrict__ p,
                                                  const float* __restrict__ scale,
                                                  const float* __restrict__ shift,
                                                  const float* __restrict__ w0,
                                                  const float* __restrict__ lng,
                                                  const float* __restrict__ lnb,
                                                  const float* __restrict__ w1,
                                                  float* __restrict__ ker) {
    const int b = blockIdx.x, c = threadIdx.x;
    __shared__ float s_w0[KS * KK], s_w1[KK * KS];
    __shared__ float r1[4], r2[4];
    for (int i = threadIdx.x; i < KS * KK; i += 256) { s_w0[i] = w0[i]; s_w1[i] = w1[i]; }
    __syncthreads();
    float pn[KK];
    const float* pp = p + ((size_t)b * CH + c) * KK;
    const float sc = scale[c], sh = shift[c];
    #pragma unroll
    for (int i = 0; i < KK; ++i) pn[i] = pp[i] * sc + sh;
    float v[KS];
    float ls = 0.f, ls2 = 0.f;
    #pragma unroll
    for (int j = 0; j < KS; ++j) {
        float a = 0.f;
        #pragma unroll
        for (int i = 0; i < KK; ++i) a += pn[i] * s_w0[j * KK + i];   // v = pn @ w0^T
        v[j] = a; ls += a; ls2 += a * a;
    }
    #pragma unroll
    for (int o = 32; o >= 1; o >>= 1) {
        ls  += __shfl_down(ls, o, 64);
        ls2 += __shfl_down(ls2, o, 64);
    }
    const int w = threadIdx.x >> 6;
    if ((threadIdx.x & 63) == 0) { r1[w] = ls; r2[w] = ls2; }
    __syncthreads();
    const float S  = r1[0] + r1[1] + r1[2] + r1[3];
    const float S2 = r2[0] + r2[1] + r2[2] + r2[3];
    const float inv = 1.0f / (float)(CH * KS);
    const float m   = S * inv;
    const float var = S2 * inv - m * m;             // biased, matches ref
    const float rs  = rsqrtf(var + 1e-5f);
    float sg[KS];
    #pragma unroll
    for (int j = 0; j < KS; ++j) {
        const float vn = (v[j] - m) * rs * lng[c * KS + j] + lnb[c * KS + j];
        sg[j] = 1.0f / (1.0f + expf(-vn));
    }
    float* ko = ker + ((size_t)b * CH + c) * KK;
    #pragma unroll
    for (int i = 0; i < KK; ++i) {
        float a = 0.f;
        #pragma unroll
        for (int j = 0; j < KS; ++j) a += sg[j] * s_w1[i * KS + j];   // @ w1^T
        ko[i] = a;
    }
}

// ------- Kernel 4: depthwise 7x7 'SAME' conv with per-(b,c) kernels --------
// block per (b,c); zero-padded image in LDS; thread = (col, 7-row strip)
__global__ __launch_bounds__(448) void conv_kernel(const float* __restrict__ x,
                                                   const float* __restrict__ ker,
                                                   float* __restrict__ out) {
    __shared__ float pad[PROWS * PITCH];
    __shared__ float kf[KK];
    const int img = blockIdx.x;
    const int t = threadIdx.x;
    const float* xi = x + (size_t)img * HW;
    if (t < KK) kf[t] = ker[(size_t)img * KK + t];
    for (int i = t; i < PROWS * PITCH; i += 448) {
        const int pr = i >> 6, pc = i & 63;
        const int r = pr - 3, c = pc - 3;
        float v = 0.f;
        if (r >= 0 && r < HH && c >= 0 && c < WW) v = xi[r * WW + c];
        pad[i] = v;
    }
    __syncthreads();
    const int col = t % 56;          // lane-consecutive -> conflict-free LDS, coalesced stores
    const int r0  = (t / 56) * 7;    // 7-row output strip
    float acc[7] = {0.f, 0.f, 0.f, 0.f, 0.f, 0.f, 0.f};
    #pragma unroll
    for (int kw = 0; kw < 7; ++kw) {
        float wv[13];
        #pragma unroll
        for (int rr = 0; rr < 13; ++rr) wv[rr] = pad[(r0 + rr) * PITCH + col + kw];
        #pragma unroll
        for (int kr = 0; kr < 7; ++kr) {
            const float kv = kf[kr * 7 + kw];
            #pragma unroll
            for (int rr = 0; rr < 7; ++rr) acc[rr] += wv[rr + kr] * kv;
        }
    }
    float* oi = out + (size_t)img * HW;
    #pragma unroll
    for (int rr = 0; rr < 7; ++rr) oi[(r0 + rr) * WW + col] = acc[rr];
}

extern "C" void kernel_launch(void* const* d_in, const int* in_sizes, int n_in,
                              void* d_out, int out_size, void* d_ws, size_t ws_size,
                              hipStream_t stream) {
    const float* x   = (const float*)d_in[0];
    const float* bng = (const float*)d_in[1];
    const float* bnb = (const float*)d_in[2];
    const float* w0  = (const float*)d_in[3];
    const float* lng = (const float*)d_in[4];
    const float* lnb = (const float*)d_in[5];
    const float* w1  = (const float*)d_in[6];
    float* out = (float*)d_out;

    float* ws    = (float*)d_ws;
    float* p     = ws;                       // NIMG*KK floats
    float* scale = p + (size_t)NIMG * KK;    // CH
    float* shift = scale + CH;               // CH
    float* kern  = shift + CH;               // NIMG*KK

    hipLaunchKernelGGL(pool_kernel,    dim3(NIMG),  dim3(256), 0, stream, x, p);
    hipLaunchKernelGGL(bnstats_kernel, dim3(CH),    dim3(256), 0, stream, p, bng, bnb, scale, shift);
    hipLaunchKernelGGL(mid_kernel,     dim3(BATCH), dim3(256), 0, stream, p, scale, shift,
                       w0, lng, lnb, w1, kern);
    hipLaunchKernelGGL(conv_kernel,    dim3(NIMG),  dim3(448), 0, stream, x, kern, out);
}